// Round 2
// baseline (5096.886 us; speedup 1.0000x reference)
//
#include <hip/hip_runtime.h>
#include <hip/hip_bf16.h>

#define BB 8
#define CC 256
#define NN 4096
#define KP 64   // projection dim K = C/4

// ---------------------------------------------------------------------------
// Kernel 1: channel projections (fp32)
//   f[b][n][k] = sum_c WF[k][c] * feat[b][c][n]
//   g[b][n][k] = sum_c WG[k][c] * feat[b][c][n]
//   h[b][n][d] = sum_c WH[d][c] * feat[b][c][n]
// Block: 256 threads, handles 32 columns (n) of one batch.
// feat tile [256c][32n] staged in LDS (32 KB).
// NOTE: grp = t>>5 is NOT wave-uniform (wave=64 spans two groups) — weight
// loads are per-lane VMEM (2 distinct addrs/wave, L1-resident). Round-0 bug
// was readfirstlane() here, which poisoned half of each k-range.
// ---------------------------------------------------------------------------
__global__ __launch_bounds__(256) void proj_kernel(
    const float* __restrict__ feat,
    const float* __restrict__ WF,
    const float* __restrict__ WG,
    const float* __restrict__ WH,
    float* __restrict__ fb,
    float* __restrict__ gb,
    float* __restrict__ hb)
{
    __shared__ float fs[CC][32];   // 32 KB
    const int b  = blockIdx.y;
    const int n0 = blockIdx.x * 32;
    const int t  = threadIdx.x;

    // stage feat[b][:, n0..n0+31]: 8192 floats = 2048 float4, 8 per thread
    #pragma unroll
    for (int i = 0; i < 8; i++) {
        int v = t + i * 256;          // 0..2047
        int c = v >> 3, nq = v & 7;
        *(float4*)&fs[c][nq * 4] =
            *(const float4*)(feat + ((size_t)b * CC + c) * NN + n0 + nq * 4);
    }
    __syncthreads();

    const int n   = t & 31;
    const int grp = t >> 5;          // 0..7 (per-lane; NOT wave-uniform)

    // ---- f and g: this thread computes k = grp*8 .. grp*8+7 for its n ----
    {
        const int k0 = grp * 8;
        float accF[8], accG[8];
        #pragma unroll
        for (int kk = 0; kk < 8; kk++) { accF[kk] = 0.f; accG[kk] = 0.f; }
        #pragma unroll 4
        for (int c = 0; c < CC; c++) {
            float fv = fs[c][n];
            #pragma unroll
            for (int kk = 0; kk < 8; kk++) {
                accF[kk] = fmaf(WF[(k0 + kk) * CC + c], fv, accF[kk]);
                accG[kk] = fmaf(WG[(k0 + kk) * CC + c], fv, accG[kk]);
            }
        }
        size_t base = ((size_t)b * NN + n0 + n) * KP + k0;
        float4 vf0 = {accF[0], accF[1], accF[2], accF[3]};
        float4 vf1 = {accF[4], accF[5], accF[6], accF[7]};
        float4 vg0 = {accG[0], accG[1], accG[2], accG[3]};
        float4 vg1 = {accG[4], accG[5], accG[6], accG[7]};
        *(float4*)(fb + base)     = vf0;
        *(float4*)(fb + base + 4) = vf1;
        *(float4*)(gb + base)     = vg0;
        *(float4*)(gb + base + 4) = vg1;
    }

    // ---- h: this thread computes d = grp*32 .. grp*32+31 for its n ----
    {
        const int d0 = grp * 32;
        float acc[32];
        #pragma unroll
        for (int dd = 0; dd < 32; dd++) acc[dd] = 0.f;
        #pragma unroll 2
        for (int c = 0; c < CC; c++) {
            float fv = fs[c][n];
            #pragma unroll
            for (int dd = 0; dd < 32; dd++)
                acc[dd] = fmaf(WH[(d0 + dd) * CC + c], fv, acc[dd]);
        }
        size_t base = ((size_t)b * NN + n0 + n) * CC + d0;
        #pragma unroll
        for (int dd4 = 0; dd4 < 8; dd4++) {
            float4 v = {acc[dd4 * 4 + 0], acc[dd4 * 4 + 1],
                        acc[dd4 * 4 + 2], acc[dd4 * 4 + 3]};
            *(float4*)(hb + base + dd4 * 4) = v;
        }
    }
}

// ---------------------------------------------------------------------------
// Kernel 2: flash-style attention (fp32) + fused residual epilogue
//   s[n][m] = g[n]·f[m]; beta = softmax_m(s); o[n] = beta·h; out = gamma*o+inp
// Block: 256 threads, Tq=32 queries, marches over N in Tm=32 key tiles.
// Thread t owns output channel d = t for all 32 queries (o[32] in VGPRs).
// Grid (B, N/32): consecutive blockIdx round-robins XCDs, so each batch's
// f/h working set (~5 MB) stays mostly in one XCD's L2.
// ---------------------------------------------------------------------------
__global__ __launch_bounds__(256) void attn_kernel(
    const float* __restrict__ fb,
    const float* __restrict__ gb,
    const float* __restrict__ hb,
    const float* __restrict__ inp,
    const float* __restrict__ gamma,
    float* __restrict__ out)
{
    const int b  = blockIdx.x;
    const int q0 = blockIdx.y * 32;
    const int t  = threadIdx.x;

    __shared__ float g_s[32][68];    // padded rows (272 B, 16B-aligned)
    __shared__ float f_s[32][68];
    __shared__ float h_s[32][CC];    // 32 KB
    __shared__ float w_s[32][36];    // scores -> weights (144 B rows)
    __shared__ float m_run[32], l_run[32], alpha_s[32];

    // load g tile once: 2048 floats = 512 float4
    {
        const float4* src = (const float4*)(gb + ((size_t)b * NN + q0) * KP);
        #pragma unroll
        for (int i = 0; i < 2; i++) {
            int v = t + i * 256;                 // 0..511
            *(float4*)&g_s[v >> 4][(v & 15) * 4] = src[v];
        }
    }
    if (t < 32) { m_run[t] = -1e30f; l_run[t] = 0.f; }

    float o[32];
    #pragma unroll
    for (int q = 0; q < 32; q++) o[q] = 0.f;

    const int m  = t & 31;           // this thread's key row in score phase
    const int qb = (t >> 5) * 4;     // 4 queries per thread in score phase

    #pragma unroll 1
    for (int mt = 0; mt < NN / 32; mt++) {
        const int m0 = mt * 32;
        __syncthreads();   // prev iter's PV reads of h_s/w_s are done
        // stage f tile (512 f4) and h tile (2048 f4)
        {
            const float4* src = (const float4*)(fb + ((size_t)b * NN + m0) * KP);
            #pragma unroll
            for (int i = 0; i < 2; i++) {
                int v = t + i * 256;
                *(float4*)&f_s[v >> 4][(v & 15) * 4] = src[v];
            }
            const float4* hsrc = (const float4*)(hb + ((size_t)b * NN + m0) * CC);
            #pragma unroll
            for (int i = 0; i < 8; i++) {
                int v = t + i * 256;
                *(float4*)&h_s[v >> 6][(v & 63) * 4] = hsrc[v];
            }
        }
        __syncthreads();

        // ---- scores: s[qb+j][m] = g[qb+j] · f[m], j=0..3 ----
        {
            float a0 = 0.f, a1 = 0.f, a2 = 0.f, a3 = 0.f;
            #pragma unroll
            for (int k4 = 0; k4 < 16; k4++) {
                float4 fv = *(const float4*)&f_s[m][k4 * 4];
                float4 g0 = *(const float4*)&g_s[qb + 0][k4 * 4];
                float4 g1 = *(const float4*)&g_s[qb + 1][k4 * 4];
                float4 g2 = *(const float4*)&g_s[qb + 2][k4 * 4];
                float4 g3 = *(const float4*)&g_s[qb + 3][k4 * 4];
                a0 = fmaf(g0.x, fv.x, a0); a0 = fmaf(g0.y, fv.y, a0);
                a0 = fmaf(g0.z, fv.z, a0); a0 = fmaf(g0.w, fv.w, a0);
                a1 = fmaf(g1.x, fv.x, a1); a1 = fmaf(g1.y, fv.y, a1);
                a1 = fmaf(g1.z, fv.z, a1); a1 = fmaf(g1.w, fv.w, a1);
                a2 = fmaf(g2.x, fv.x, a2); a2 = fmaf(g2.y, fv.y, a2);
                a2 = fmaf(g2.z, fv.z, a2); a2 = fmaf(g2.w, fv.w, a2);
                a3 = fmaf(g3.x, fv.x, a3); a3 = fmaf(g3.y, fv.y, a3);
                a3 = fmaf(g3.z, fv.z, a3); a3 = fmaf(g3.w, fv.w, a3);
            }
            w_s[qb + 0][m] = a0;
            w_s[qb + 1][m] = a1;
            w_s[qb + 2][m] = a2;
            w_s[qb + 3][m] = a3;
        }
        __syncthreads();

        // ---- online softmax update, one lane per query row ----
        if (t < 32) {
            float mprev = m_run[t];
            float rmax  = mprev;
            #pragma unroll
            for (int j = 0; j < 32; j++) rmax = fmaxf(rmax, w_s[t][j]);
            float al  = __expf(mprev - rmax);
            float sum = 0.f;
            #pragma unroll
            for (int j = 0; j < 32; j++) {
                float w = __expf(w_s[t][j] - rmax);
                w_s[t][j] = w;
                sum += w;
            }
            l_run[t]   = l_run[t] * al + sum;
            m_run[t]   = rmax;
            alpha_s[t] = al;
        }
        __syncthreads();

        // ---- PV accumulate: o[q] = o[q]*alpha + sum_m w[q][m] * h[m][d=t] ----
        {
            #pragma unroll
            for (int q = 0; q < 32; q++) o[q] *= alpha_s[q];
            #pragma unroll
            for (int mm = 0; mm < 32; mm += 4) {
                float h0 = h_s[mm + 0][t];
                float h1 = h_s[mm + 1][t];
                float h2 = h_s[mm + 2][t];
                float h3 = h_s[mm + 3][t];
                #pragma unroll
                for (int q = 0; q < 32; q++) {
                    float4 wv = *(const float4*)&w_s[q][mm];   // broadcast
                    o[q] = fmaf(wv.x, h0, o[q]);
                    o[q] = fmaf(wv.y, h1, o[q]);
                    o[q] = fmaf(wv.z, h2, o[q]);
                    o[q] = fmaf(wv.w, h3, o[q]);
                }
            }
        }
    }

    // ---- epilogue: out = gamma * (o/l) + input, raw-reshape layout ----
    const float gam = gamma[0];
    #pragma unroll
    for (int q = 0; q < 32; q++) {
        float val = o[q] / l_run[q];
        size_t idx = ((size_t)b * NN + q0 + q) * CC + t;
        out[idx] = fmaf(gam, val, inp[idx]);
    }
}

// ---------------------------------------------------------------------------
extern "C" void kernel_launch(void* const* d_in, const int* in_sizes, int n_in,
                              void* d_out, int out_size, void* d_ws, size_t ws_size,
                              hipStream_t stream) {
    const float* input = (const float*)d_in[0];
    const float* nms   = (const float*)d_in[1];   // feat = nms_feat
    const float* WF    = (const float*)d_in[2];
    const float* WG    = (const float*)d_in[3];
    const float* WH    = (const float*)d_in[4];
    const float* gamma = (const float*)d_in[5];
    float* out = (float*)d_out;

    // workspace: f [B][N][K], g [B][N][K], h [B][N][C]  -> ~50.3 MB fp32
    float* ws = (float*)d_ws;
    float* fb = ws;
    float* gb = ws + (size_t)BB * NN * KP;
    float* hb = ws + 2 * (size_t)BB * NN * KP;

    proj_kernel<<<dim3(NN / 32, BB), 256, 0, stream>>>(nms, WF, WG, WH, fb, gb, hb);
    attn_kernel<<<dim3(BB, NN / 32), 256, 0, stream>>>(fb, gb, hb, input, gamma, out);
}

// Round 3
// 416.158 us; speedup vs baseline: 12.2475x; 12.2475x over previous
//
#include <hip/hip_runtime.h>
#include <hip/hip_bf16.h>

#define BB 8
#define CC 256
#define NN 4096
#define KP 64   // projection dim K = C/4

typedef _Float16 f16x8 __attribute__((ext_vector_type(8)));
typedef _Float16 f16x4 __attribute__((ext_vector_type(4)));
typedef float    f32x4 __attribute__((ext_vector_type(4)));

#define MFMA16(a, b, c) __builtin_amdgcn_mfma_f32_16x16x32_f16((a), (b), (c), 0, 0, 0)

// ---------------------------------------------------------------------------
// Kernel 0: convert WF|WG|WH (fp32) to one concatenated fp16 matrix W16[384][256].
// Rows 0-63 = WF, 64-127 = WG, 128-383 = WH.
// ---------------------------------------------------------------------------
__global__ __launch_bounds__(256) void wconv_kernel(
    const float* __restrict__ WF, const float* __restrict__ WG,
    const float* __restrict__ WH, _Float16* __restrict__ W16)
{
    int gid = blockIdx.x * 256 + threadIdx.x;   // 0..24575
    int i4  = gid * 4;
    const float* src;
    if (i4 < 64 * CC)        src = WF + i4;
    else if (i4 < 128 * CC)  src = WG + (i4 - 64 * CC);
    else                     src = WH + (i4 - 128 * CC);
    float4 v = *(const float4*)src;
    f16x4 o = { (_Float16)v.x, (_Float16)v.y, (_Float16)v.z, (_Float16)v.w };
    *(f16x4*)(W16 + i4) = o;
}

// ---------------------------------------------------------------------------
// Kernel 1: fp16 MFMA projection. D[out=384][tok=32] = W16[384][256] x feat[256][32].
// Block: 256 thr (4 waves), wave w owns out-rows [w*96, w*96+96).
// feat tile staged TRANSPOSED as fp16 ft[tok][c] so B-frags are contiguous 16B.
// Outputs written directly in attention layouts:
//   f,g: [b][n][64] fp16 (QK^T operand rows), h: TRANSPOSED [b][d][n] fp16 (PV B rows).
// ---------------------------------------------------------------------------
__global__ __launch_bounds__(256, 4) void proj16_kernel(
    const float* __restrict__ feat, const _Float16* __restrict__ W16,
    _Float16* __restrict__ fb, _Float16* __restrict__ gb,
    _Float16* __restrict__ hT)
{
    __shared__ __align__(16) _Float16 ft[32][264];   // +8 pad: conflict-light
    const int b = blockIdx.y, n0 = blockIdx.x * 32, t = threadIdx.x;

    // stage feat[b][:, n0..n0+31] -> ft[tok][c] fp16 (transpose + convert)
    #pragma unroll
    for (int i = 0; i < 8; i++) {
        int v = t + i * 256, c = v >> 3, nq = v & 7;
        float4 x = *(const float4*)(feat + ((size_t)b * CC + c) * NN + n0 + nq * 4);
        ft[nq * 4 + 0][c] = (_Float16)x.x;
        ft[nq * 4 + 1][c] = (_Float16)x.y;
        ft[nq * 4 + 2][c] = (_Float16)x.z;
        ft[nq * 4 + 3][c] = (_Float16)x.w;
    }
    __syncthreads();

    const int w = t >> 6, lane = t & 63, quad = lane >> 4, ln = lane & 15;
    const int rowbase = w * 96;

    f32x4 acc[6][2] = {};
    #pragma unroll
    for (int ks = 0; ks < 8; ks++) {
        const int c0 = ks * 32;
        f16x8 bfr[2];
        #pragma unroll
        for (int tf = 0; tf < 2; tf++)
            bfr[tf] = *(const f16x8*)&ft[tf * 16 + ln][c0 + quad * 8];
        #pragma unroll
        for (int af = 0; af < 6; af++) {
            f16x8 a = *(const f16x8*)(W16 + (size_t)(rowbase + af * 16 + ln) * CC + c0 + quad * 8);
            acc[af][0] = MFMA16(a, bfr[0], acc[af][0]);
            acc[af][1] = MFMA16(a, bfr[1], acc[af][1]);
        }
    }

    // scatter-store per C/D layout: row(out) = quad*4+r, col(tok) = ln
    #pragma unroll
    for (int af = 0; af < 6; af++) {
        #pragma unroll
        for (int tf = 0; tf < 2; tf++) {
            #pragma unroll
            for (int r = 0; r < 4; r++) {
                int orow = rowbase + af * 16 + quad * 4 + r;
                int tok  = n0 + tf * 16 + ln;
                _Float16 val = (_Float16)acc[af][tf][r];
                if (orow < 64)
                    fb[((size_t)b * NN + tok) * KP + orow] = val;
                else if (orow < 128)
                    gb[((size_t)b * NN + tok) * KP + (orow - 64)] = val;
                else
                    hT[((size_t)b * CC + (orow - 128)) * NN + tok] = val;
            }
        }
    }
}

// ---------------------------------------------------------------------------
// Kernel 2: fp16 MFMA flash attention + fused residual epilogue.
// Block 256 thr, Tq=32 queries, K-tiles Tm=64. Wave w owns channels [w*64, w*64+64).
// Waves 0,1: QK^T (16q stripes) + online softmax in-register; P -> LDS fp16.
// All waves: PV with h^T B-frags PREFETCHED from global (L2-resident, no LDS).
// LDS ~18.7 KB -> 4 blocks/CU (grid 1024 = exactly 4/CU).
// Grid (b, qt): linear id = b + 8*qt -> XCD = b, batch working set stays in one L2.
// ---------------------------------------------------------------------------
__global__ __launch_bounds__(256, 4) void attn16_kernel(
    const _Float16* __restrict__ fb, const _Float16* __restrict__ gb,
    const _Float16* __restrict__ hT, const float* __restrict__ inp,
    const float* __restrict__ gamma, float* __restrict__ out)
{
    __shared__ __align__(16) _Float16 g_s[32][72];
    __shared__ __align__(16) _Float16 f_s[64][72];
    __shared__ __align__(16) _Float16 p_s[32][72];
    __shared__ float alpha_s[32], l_s[32];

    const int b = blockIdx.x, q0 = blockIdx.y * 32, t = threadIdx.x;
    const int w = t >> 6, lane = t & 63, quad = lane >> 4, ln = lane & 15;

    // stage g tile [32 q][64 k] (once)
    {
        int row = t >> 3, kc = t & 7;
        *(f16x8*)&g_s[row][kc * 8] =
            *(const f16x8*)(gb + ((size_t)b * NN + q0 + row) * KP + kc * 8);
    }

    float m_run[4] = {-1e30f, -1e30f, -1e30f, -1e30f};
    float l_run[4] = {0.f, 0.f, 0.f, 0.f};
    f32x4 acc[2][4] = {};
    const int dbase = w * 64;

    #pragma unroll 1
    for (int mt = 0; mt < NN / 64; mt++) {
        const int m0 = mt * 64;

        // prefetch h^T B-frags for this K-tile straight from global (L2)
        f16x8 hv[2][4];
        #pragma unroll
        for (int ks = 0; ks < 2; ks++)
            #pragma unroll
            for (int df = 0; df < 4; df++)
                hv[ks][df] = *(const f16x8*)(hT +
                    ((size_t)b * CC + dbase + df * 16 + ln) * NN + m0 + ks * 32 + quad * 8);

        // stage f tile [64 m][64 k]
        #pragma unroll
        for (int i = 0; i < 2; i++) {
            int v = t + i * 256, m = v >> 3, kc = v & 7;
            *(f16x8*)&f_s[m][kc * 8] =
                *(const f16x8*)(fb + ((size_t)b * NN + m0 + m) * KP + kc * 8);
        }
        __syncthreads();   // f_s ready; prev-iter p_s readers all passed

        if (w < 2) {
            // ---- S = g . f^T for q-stripe [w*16, w*16+16) ----
            f32x4 S[4] = {};
            #pragma unroll
            for (int ks = 0; ks < 2; ks++) {
                f16x8 ag = *(const f16x8*)&g_s[w * 16 + ln][ks * 32 + quad * 8];
                #pragma unroll
                for (int mf = 0; mf < 4; mf++) {
                    f16x8 bf = *(const f16x8*)&f_s[mf * 16 + ln][ks * 32 + quad * 8];
                    S[mf] = MFMA16(ag, bf, S[mf]);
                }
            }
            // ---- online softmax, rows q = w*16 + quad*4 + r ----
            #pragma unroll
            for (int r = 0; r < 4; r++) {
                float mx = fmaxf(fmaxf(S[0][r], S[1][r]), fmaxf(S[2][r], S[3][r]));
                #pragma unroll
                for (int msk = 1; msk < 16; msk <<= 1)
                    mx = fmaxf(mx, __shfl_xor(mx, msk));
                float mnew = fmaxf(m_run[r], mx);
                float al   = __expf(m_run[r] - mnew);
                float sum  = 0.f;
                #pragma unroll
                for (int mf = 0; mf < 4; mf++) {
                    float p = __expf(S[mf][r] - mnew);
                    S[mf][r] = p;
                    sum += p;
                }
                #pragma unroll
                for (int msk = 1; msk < 16; msk <<= 1)
                    sum += __shfl_xor(sum, msk);
                l_run[r] = l_run[r] * al + sum;
                m_run[r] = mnew;
                if (ln == 0) alpha_s[w * 16 + quad * 4 + r] = al;
                #pragma unroll
                for (int mf = 0; mf < 4; mf++)
                    p_s[w * 16 + quad * 4 + r][mf * 16 + ln] = (_Float16)S[mf][r];
            }
        }
        __syncthreads();   // p_s + alpha_s visible

        // ---- PV: acc[q][d] = acc*alpha + P x h^T ----
        float al_[2][4];
        #pragma unroll
        for (int qf = 0; qf < 2; qf++)
            #pragma unroll
            for (int r = 0; r < 4; r++)
                al_[qf][r] = alpha_s[qf * 16 + quad * 4 + r];
        #pragma unroll
        for (int qf = 0; qf < 2; qf++)
            #pragma unroll
            for (int df = 0; df < 4; df++)
                #pragma unroll
                for (int r = 0; r < 4; r++)
                    acc[qf][df][r] *= al_[qf][r];
        #pragma unroll
        for (int ks = 0; ks < 2; ks++) {
            #pragma unroll
            for (int qf = 0; qf < 2; qf++) {
                f16x8 ap = *(const f16x8*)&p_s[qf * 16 + ln][ks * 32 + quad * 8];
                #pragma unroll
                for (int df = 0; df < 4; df++)
                    acc[qf][df] = MFMA16(ap, hv[ks][df], acc[qf][df]);
            }
        }
    }

    __syncthreads();
    if (w < 2 && ln == 0) {
        #pragma unroll
        for (int r = 0; r < 4; r++)
            l_s[w * 16 + quad * 4 + r] = l_run[r];
    }
    __syncthreads();

    // ---- epilogue: out = gamma*(o/l) + input (raw-reshape flat layout) ----
    const float gam = gamma[0];
    #pragma unroll
    for (int qf = 0; qf < 2; qf++) {
        #pragma unroll
        for (int r = 0; r < 4; r++) {
            int q = qf * 16 + quad * 4 + r;
            float linv = 1.0f / l_s[q];
            #pragma unroll
            for (int df = 0; df < 4; df++) {
                int d = dbase + df * 16 + ln;
                size_t idx = ((size_t)b * NN + q0 + q) * CC + d;
                out[idx] = fmaf(gam, acc[qf][df][r] * linv, inp[idx]);
            }
        }
    }
}

// ---------------------------------------------------------------------------
extern "C" void kernel_launch(void* const* d_in, const int* in_sizes, int n_in,
                              void* d_out, int out_size, void* d_ws, size_t ws_size,
                              hipStream_t stream) {
    const float* input = (const float*)d_in[0];
    const float* nms   = (const float*)d_in[1];
    const float* WF    = (const float*)d_in[2];
    const float* WG    = (const float*)d_in[3];
    const float* WH    = (const float*)d_in[4];
    const float* gamma = (const float*)d_in[5];
    float* out = (float*)d_out;

    // workspace: W16 (192 KB) | fb16 (4 MB) | gb16 (4 MB) | hT16 (16 MB) = 25.4 MB
    char* ws = (char*)d_ws;
    _Float16* W16  = (_Float16*)ws;
    _Float16* fb16 = (_Float16*)(ws + 196608);
    _Float16* gb16 = (_Float16*)(ws + 196608 + 4194304);
    _Float16* hT16 = (_Float16*)(ws + 196608 + 2 * 4194304);

    wconv_kernel<<<96, 256, 0, stream>>>(WF, WG, WH, W16);
    proj16_kernel<<<dim3(NN / 32, BB), 256, 0, stream>>>(nms, W16, fb16, gb16, hT16);
    attn16_kernel<<<dim3(BB, NN / 32), 256, 0, stream>>>(fb16, gb16, hT16, input, gamma, out);
}

// Round 4
// 269.117 us; speedup vs baseline: 18.9393x; 1.5464x over previous
//
#include <hip/hip_runtime.h>
#include <hip/hip_bf16.h>

#define BB 8
#define CC 256
#define NN 4096
#define KP 64   // projection dim K = C/4

typedef _Float16 f16x8 __attribute__((ext_vector_type(8)));
typedef _Float16 f16x4 __attribute__((ext_vector_type(4)));
typedef float    f32x4 __attribute__((ext_vector_type(4)));

#define MFMA16(a, b, c) __builtin_amdgcn_mfma_f32_16x16x32_f16((a), (b), (c), 0, 0, 0)

// 16-lane (DPP-row) rotate: VALU-speed cross-lane, keeps softmax off the LDS pipe
template<int CTRL>
__device__ __forceinline__ float dpp_ror_f(float x) {
    return __int_as_float(__builtin_amdgcn_update_dpp(
        0, __float_as_int(x), CTRL, 0xF, 0xF, true));
}
__device__ __forceinline__ float max16(float x) {
    x = fmaxf(x, dpp_ror_f<0x128>(x));   // row_ror:8
    x = fmaxf(x, dpp_ror_f<0x124>(x));   // row_ror:4
    x = fmaxf(x, dpp_ror_f<0x122>(x));   // row_ror:2
    x = fmaxf(x, dpp_ror_f<0x121>(x));   // row_ror:1
    return x;
}
__device__ __forceinline__ float sum16(float x) {
    x += dpp_ror_f<0x128>(x);
    x += dpp_ror_f<0x124>(x);
    x += dpp_ror_f<0x122>(x);
    x += dpp_ror_f<0x121>(x);
    return x;
}

// ---------------------------------------------------------------------------
// Kernel 0: WF|WG|WH fp32 -> concatenated fp16 W16[384][256].
// ---------------------------------------------------------------------------
__global__ __launch_bounds__(256) void wconv_kernel(
    const float* __restrict__ WF, const float* __restrict__ WG,
    const float* __restrict__ WH, _Float16* __restrict__ W16)
{
    int gid = blockIdx.x * 256 + threadIdx.x;
    int i4  = gid * 4;
    const float* src;
    if (i4 < 64 * CC)        src = WF + i4;
    else if (i4 < 128 * CC)  src = WG + (i4 - 64 * CC);
    else                     src = WH + (i4 - 128 * CC);
    float4 v = *(const float4*)src;
    f16x4 o = { (_Float16)v.x, (_Float16)v.y, (_Float16)v.z, (_Float16)v.w };
    *(f16x4*)(W16 + i4) = o;
}

// ---------------------------------------------------------------------------
// Kernel 1: fp16 MFMA projection.  D[384 out][32 tok] = W16 x feat.
// f,g written [b][n][64] (packed b64: 4 consecutive k per lane).
// h written TRANSPOSED+PERMUTED: hT[b][d][col], col = tilebase + (tok&15)*4
// + ((tok>>4)&3) — matches attn's p_s column permutation so both p_s writes
// and hv B-frag reads are contiguous.
// ---------------------------------------------------------------------------
__global__ __launch_bounds__(256, 4) void proj16_kernel(
    const float* __restrict__ feat, const _Float16* __restrict__ W16,
    _Float16* __restrict__ fb, _Float16* __restrict__ gb,
    _Float16* __restrict__ hT)
{
    __shared__ __align__(16) _Float16 ft[32][264];
    const int b = blockIdx.y, n0 = blockIdx.x * 32, t = threadIdx.x;

    #pragma unroll
    for (int i = 0; i < 8; i++) {
        int v = t + i * 256, c = v >> 3, nq = v & 7;
        float4 x = *(const float4*)(feat + ((size_t)b * CC + c) * NN + n0 + nq * 4);
        ft[nq * 4 + 0][c] = (_Float16)x.x;
        ft[nq * 4 + 1][c] = (_Float16)x.y;
        ft[nq * 4 + 2][c] = (_Float16)x.z;
        ft[nq * 4 + 3][c] = (_Float16)x.w;
    }
    __syncthreads();

    const int w = t >> 6, lane = t & 63, quad = lane >> 4, ln = lane & 15;
    const int rowbase = w * 96;

    f32x4 acc[6][2] = {};
    #pragma unroll
    for (int ks = 0; ks < 8; ks++) {
        const int c0 = ks * 32;
        f16x8 bfr[2];
        #pragma unroll
        for (int tf = 0; tf < 2; tf++)
            bfr[tf] = *(const f16x8*)&ft[tf * 16 + ln][c0 + quad * 8];
        #pragma unroll
        for (int af = 0; af < 6; af++) {
            f16x8 a = *(const f16x8*)(W16 + (size_t)(rowbase + af * 16 + ln) * CC + c0 + quad * 8);
            acc[af][0] = MFMA16(a, bfr[0], acc[af][0]);
            acc[af][1] = MFMA16(a, bfr[1], acc[af][1]);
        }
    }

    // C/D layout: col(tok)=ln, row(out)=quad*4+r  ->  r spans 4 consecutive k
    #pragma unroll
    for (int af = 0; af < 6; af++) {
        const int orow0 = rowbase + af * 16 + quad * 4;
        #pragma unroll
        for (int tf = 0; tf < 2; tf++) {
            const int tok = n0 + tf * 16 + ln;
            f16x4 pk = { (_Float16)acc[af][tf][0], (_Float16)acc[af][tf][1],
                         (_Float16)acc[af][tf][2], (_Float16)acc[af][tf][3] };
            if (orow0 < 64) {
                *(f16x4*)(fb + ((size_t)b * NN + tok) * KP + orow0) = pk;
            } else if (orow0 < 128) {
                *(f16x4*)(gb + ((size_t)b * NN + tok) * KP + (orow0 - 64)) = pk;
            } else {
                const int col = (n0 & ~63) + ((tok & 15) * 4) + ((tok >> 4) & 3);
                #pragma unroll
                for (int r = 0; r < 4; r++)
                    hT[((size_t)b * CC + (orow0 - 128 + r)) * NN + col] = pk[r];
            }
        }
    }
}

// ---------------------------------------------------------------------------
// Kernel 2: fp16 MFMA flash attention, Tq=64, Tm=64, 4 symmetric waves.
// Wave w: QK^T + online softmax (DPP reductions) for q-stripe [w*16,w*16+16),
// then PV for channels [w*64, w*64+64) over all 64 queries.
// P round-trips LDS with permuted columns (m' = ln*4+mf -> packed b64 write).
// hv B-frags + next f-tile double-buffered in registers from L2-resident hT/fb.
// Grid (b, qt): linear id = b + 8*qt -> XCD = b; per-batch f+g+hT = 3 MB < L2.
// ---------------------------------------------------------------------------
__global__ __launch_bounds__(256, 2) void attn16_kernel(
    const _Float16* __restrict__ fb, const _Float16* __restrict__ gb,
    const _Float16* __restrict__ hT, const float* __restrict__ inp,
    const float* __restrict__ gamma, float* __restrict__ out)
{
    __shared__ __align__(16) _Float16 g_s[64][72];
    __shared__ __align__(16) _Float16 f_s[64][72];
    __shared__ __align__(16) _Float16 p_s[64][72];
    __shared__ float alpha_s[64];
    __shared__ float l_s[64];

    const int b = blockIdx.x, q0 = blockIdx.y * 64, t = threadIdx.x;
    const int w = t >> 6, lane = t & 63, quad = lane >> 4, ln = lane & 15;
    const int row = t >> 2, kq = t & 3;       // staging assignment
    const int dbase = w * 64;

    // stage g tile [64 q][64 k] once
    {
        const _Float16* src = gb + ((size_t)b * NN + q0 + row) * KP + kq * 16;
        *(f16x8*)&g_s[row][kq * 16]     = *(const f16x8*)(src);
        *(f16x8*)&g_s[row][kq * 16 + 8] = *(const f16x8*)(src + 8);
    }

    float m_run[4] = {-1e30f, -1e30f, -1e30f, -1e30f};
    float l_run[4] = {0.f, 0.f, 0.f, 0.f};
    f32x4 acc[4][4] = {};

    // preload tile 0 (f regs + hv regs)
    f16x8 fr[2][2];
    f16x8 hv[2][2][4];
    {
        const _Float16* src = fb + ((size_t)b * NN + row) * KP + kq * 16;
        fr[0][0] = *(const f16x8*)(src);
        fr[0][1] = *(const f16x8*)(src + 8);
        #pragma unroll
        for (int ks = 0; ks < 2; ks++)
            #pragma unroll
            for (int df = 0; df < 4; df++)
                hv[0][ks][df] = *(const f16x8*)(hT +
                    ((size_t)b * CC + dbase + df * 16 + ln) * NN + ks * 32 + quad * 8);
    }

    #pragma unroll 2
    for (int mt = 0; mt < NN / 64; mt++) {
        const int par = mt & 1, nxt = par ^ 1;
        const int m0n = ((mt + 1) & 63) * 64;   // clamped wrap: harmless reload

        // current f tile regs -> LDS
        *(f16x8*)&f_s[row][kq * 16]     = fr[par][0];
        *(f16x8*)&f_s[row][kq * 16 + 8] = fr[par][1];

        // issue next-tile prefetches (full iteration to cover L2 latency)
        {
            const _Float16* src = fb + ((size_t)b * NN + m0n + row) * KP + kq * 16;
            fr[nxt][0] = *(const f16x8*)(src);
            fr[nxt][1] = *(const f16x8*)(src + 8);
            #pragma unroll
            for (int ks = 0; ks < 2; ks++)
                #pragma unroll
                for (int df = 0; df < 4; df++)
                    hv[nxt][ks][df] = *(const f16x8*)(hT +
                        ((size_t)b * CC + dbase + df * 16 + ln) * NN + m0n + ks * 32 + quad * 8);
        }
        __syncthreads();   // f_s ready; prev iter's p_s readers all done

        // ---- QK^T for this wave's q-stripe ----
        f32x4 S[4] = {};
        #pragma unroll
        for (int ks = 0; ks < 2; ks++) {
            f16x8 ag = *(const f16x8*)&g_s[w * 16 + ln][ks * 32 + quad * 8];
            #pragma unroll
            for (int mf = 0; mf < 4; mf++) {
                f16x8 bf = *(const f16x8*)&f_s[mf * 16 + ln][ks * 32 + quad * 8];
                S[mf] = MFMA16(ag, bf, S[mf]);
            }
        }

        // ---- online softmax (rows q = w*16 + quad*4 + r), DPP reductions ----
        #pragma unroll
        for (int r = 0; r < 4; r++) {
            float mx = fmaxf(fmaxf(S[0][r], S[1][r]), fmaxf(S[2][r], S[3][r]));
            mx = max16(mx);
            float mnew = fmaxf(m_run[r], mx);
            float al   = __expf(m_run[r] - mnew);
            float p0 = __expf(S[0][r] - mnew);
            float p1 = __expf(S[1][r] - mnew);
            float p2 = __expf(S[2][r] - mnew);
            float p3 = __expf(S[3][r] - mnew);
            float sum = sum16((p0 + p1) + (p2 + p3));
            l_run[r] = l_run[r] * al + sum;
            m_run[r] = mnew;
            const int qrow = w * 16 + quad * 4 + r;
            if (ln == 0) alpha_s[qrow] = al;
            // permuted col m' = ln*4 + mf -> one packed b64 write
            f16x4 pk = { (_Float16)p0, (_Float16)p1, (_Float16)p2, (_Float16)p3 };
            *(f16x4*)&p_s[qrow][ln * 4] = pk;
        }
        __syncthreads();   // p_s + alpha_s visible

        // ---- PV: rescale + P x h^T over this wave's 64 channels ----
        #pragma unroll
        for (int qf = 0; qf < 4; qf++) {
            float a0 = alpha_s[qf * 16 + quad * 4 + 0];
            float a1 = alpha_s[qf * 16 + quad * 4 + 1];
            float a2 = alpha_s[qf * 16 + quad * 4 + 2];
            float a3 = alpha_s[qf * 16 + quad * 4 + 3];
            #pragma unroll
            for (int df = 0; df < 4; df++) {
                acc[qf][df][0] *= a0;
                acc[qf][df][1] *= a1;
                acc[qf][df][2] *= a2;
                acc[qf][df][3] *= a3;
            }
        }
        #pragma unroll
        for (int ks = 0; ks < 2; ks++) {
            #pragma unroll
            for (int qf = 0; qf < 4; qf++) {
                f16x8 ap = *(const f16x8*)&p_s[qf * 16 + ln][ks * 32 + quad * 8];
                #pragma unroll
                for (int df = 0; df < 4; df++)
                    acc[qf][df] = MFMA16(ap, hv[par][ks][df], acc[qf][df]);
            }
        }
    }

    // ---- exchange l across waves, fused epilogue ----
    if (ln == 0) {
        #pragma unroll
        for (int r = 0; r < 4; r++) l_s[w * 16 + quad * 4 + r] = l_run[r];
    }
    __syncthreads();

    const float gam = gamma[0];
    #pragma unroll
    for (int qf = 0; qf < 4; qf++) {
        #pragma unroll
        for (int r = 0; r < 4; r++) {
            const int q = qf * 16 + quad * 4 + r;
            const float linv = 1.0f / l_s[q];
            #pragma unroll
            for (int df = 0; df < 4; df++) {
                const int d = dbase + df * 16 + ln;
                size_t idx = ((size_t)b * NN + q0 + q) * CC + d;
                out[idx] = fmaf(gam, acc[qf][df][r] * linv, inp[idx]);
            }
        }
    }
}

// ---------------------------------------------------------------------------
extern "C" void kernel_launch(void* const* d_in, const int* in_sizes, int n_in,
                              void* d_out, int out_size, void* d_ws, size_t ws_size,
                              hipStream_t stream) {
    const float* input = (const float*)d_in[0];
    const float* nms   = (const float*)d_in[1];
    const float* WF    = (const float*)d_in[2];
    const float* WG    = (const float*)d_in[3];
    const float* WH    = (const float*)d_in[4];
    const float* gamma = (const float*)d_in[5];
    float* out = (float*)d_out;

    // workspace: W16 (192 KB) | fb16 (4 MB) | gb16 (4 MB) | hT16 (16 MB)
    char* ws = (char*)d_ws;
    _Float16* W16  = (_Float16*)ws;
    _Float16* fb16 = (_Float16*)(ws + 196608);
    _Float16* gb16 = (_Float16*)(ws + 196608 + 4194304);
    _Float16* hT16 = (_Float16*)(ws + 196608 + 2 * 4194304);

    wconv_kernel<<<96, 256, 0, stream>>>(WF, WG, WH, W16);
    proj16_kernel<<<dim3(NN / 32, BB), 256, 0, stream>>>(nms, W16, fb16, gb16, hT16);
    attn16_kernel<<<dim3(BB, NN / 64), 256, 0, stream>>>(fb16, gb16, hT16, input, gamma, out);
}

// Round 5
// 257.455 us; speedup vs baseline: 19.7972x; 1.0453x over previous
//
#include <hip/hip_runtime.h>
#include <hip/hip_bf16.h>

#define BB 8
#define CC 256
#define NN 4096
#define KP 64   // projection dim K = C/4
#define LOG2E 1.44269504088896f

typedef _Float16 f16x8 __attribute__((ext_vector_type(8)));
typedef _Float16 f16x4 __attribute__((ext_vector_type(4)));
typedef float    f32x4 __attribute__((ext_vector_type(4)));

#define MFMA16(a, b, c) __builtin_amdgcn_mfma_f32_16x16x32_f16((a), (b), (c), 0, 0, 0)

// exp2 (g is pre-scaled by log2e in proj, so softmax runs in base-2)
__device__ __forceinline__ float fast_exp2(float x) {
#if __has_builtin(__builtin_amdgcn_exp2f)
    return __builtin_amdgcn_exp2f(x);
#else
    return __expf(x * 0.69314718055994531f);
#endif
}

// 16-lane (DPP-row) rotate reductions: VALU-speed, off the LDS pipe
template<int CTRL>
__device__ __forceinline__ float dpp_ror_f(float x) {
    return __int_as_float(__builtin_amdgcn_update_dpp(
        0, __float_as_int(x), CTRL, 0xF, 0xF, true));
}
__device__ __forceinline__ float max16(float x) {
    x = fmaxf(x, dpp_ror_f<0x128>(x));
    x = fmaxf(x, dpp_ror_f<0x124>(x));
    x = fmaxf(x, dpp_ror_f<0x122>(x));
    x = fmaxf(x, dpp_ror_f<0x121>(x));
    return x;
}
__device__ __forceinline__ float sum16(float x) {
    x += dpp_ror_f<0x128>(x);
    x += dpp_ror_f<0x124>(x);
    x += dpp_ror_f<0x122>(x);
    x += dpp_ror_f<0x121>(x);
    return x;
}

// ---------------------------------------------------------------------------
// Kernel 0: WF|WG|WH fp32 -> concatenated fp16 W16[384][256].
// ---------------------------------------------------------------------------
__global__ __launch_bounds__(256) void wconv_kernel(
    const float* __restrict__ WF, const float* __restrict__ WG,
    const float* __restrict__ WH, _Float16* __restrict__ W16)
{
    int gid = blockIdx.x * 256 + threadIdx.x;
    int i4  = gid * 4;
    const float* src;
    if (i4 < 64 * CC)        src = WF + i4;
    else if (i4 < 128 * CC)  src = WG + (i4 - 64 * CC);
    else                     src = WH + (i4 - 128 * CC);
    float4 v = *(const float4*)src;
    f16x4 o = { (_Float16)v.x, (_Float16)v.y, (_Float16)v.z, (_Float16)v.w };
    *(f16x4*)(W16 + i4) = o;
}

// ---------------------------------------------------------------------------
// Kernel 1: fp16 MFMA projection, 64-token tiles.
// D[384 out][64 tok] = W16 x feat. Wave w owns out-rows [w*96, w*96+96).
// g rows are pre-scaled by log2e (softmax invariant; lets attn use raw exp2).
// hT stores: with 4 token-frags, permuted col = ln*4 + tf is contiguous per
// lane -> packed b64 stores (was 32 scalar b16 in the 32-token version).
// ---------------------------------------------------------------------------
__global__ __launch_bounds__(256, 3) void proj16_kernel(
    const float* __restrict__ feat, const _Float16* __restrict__ W16,
    _Float16* __restrict__ fb, _Float16* __restrict__ gb,
    _Float16* __restrict__ hT)
{
    __shared__ __align__(16) _Float16 ft[64][264];
    const int b = blockIdx.y, n0 = blockIdx.x * 64, t = threadIdx.x;

    // stage feat[b][:, n0..n0+63] -> ft[tok][c] fp16 (transpose + convert)
    #pragma unroll
    for (int i = 0; i < 16; i++) {
        int v = t + i * 256, c = v >> 4, nq = v & 15;
        float4 x = *(const float4*)(feat + ((size_t)b * CC + c) * NN + n0 + nq * 4);
        ft[nq * 4 + 0][c] = (_Float16)x.x;
        ft[nq * 4 + 1][c] = (_Float16)x.y;
        ft[nq * 4 + 2][c] = (_Float16)x.z;
        ft[nq * 4 + 3][c] = (_Float16)x.w;
    }
    __syncthreads();

    const int w = t >> 6, lane = t & 63, quad = lane >> 4, ln = lane & 15;
    const int rowbase = w * 96;

    f32x4 acc[6][4] = {};
    #pragma unroll
    for (int ks = 0; ks < 8; ks++) {
        const int c0 = ks * 32;
        f16x8 bfr[4];
        #pragma unroll
        for (int tf = 0; tf < 4; tf++)
            bfr[tf] = *(const f16x8*)&ft[tf * 16 + ln][c0 + quad * 8];
        #pragma unroll
        for (int af = 0; af < 6; af++) {
            f16x8 a = *(const f16x8*)(W16 + (size_t)(rowbase + af * 16 + ln) * CC + c0 + quad * 8);
            #pragma unroll
            for (int tf = 0; tf < 4; tf++)
                acc[af][tf] = MFMA16(a, bfr[tf], acc[af][tf]);
        }
    }

    // C/D layout: col(tok)=ln, row(out)=quad*4+r
    #pragma unroll
    for (int af = 0; af < 6; af++) {
        const int orow0 = rowbase + af * 16 + quad * 4;   // wave-uniform range
        if (orow0 < 64) {
            #pragma unroll
            for (int tf = 0; tf < 4; tf++) {
                const int tok = n0 + tf * 16 + ln;
                f16x4 pk = { (_Float16)acc[af][tf][0], (_Float16)acc[af][tf][1],
                             (_Float16)acc[af][tf][2], (_Float16)acc[af][tf][3] };
                *(f16x4*)(fb + ((size_t)b * NN + tok) * KP + orow0) = pk;
            }
        } else if (orow0 < 128) {
            #pragma unroll
            for (int tf = 0; tf < 4; tf++) {
                const int tok = n0 + tf * 16 + ln;
                f16x4 pk = { (_Float16)(acc[af][tf][0] * LOG2E),
                             (_Float16)(acc[af][tf][1] * LOG2E),
                             (_Float16)(acc[af][tf][2] * LOG2E),
                             (_Float16)(acc[af][tf][3] * LOG2E) };
                *(f16x4*)(gb + ((size_t)b * NN + tok) * KP + (orow0 - 64)) = pk;
            }
        } else {
            #pragma unroll
            for (int r = 0; r < 4; r++) {
                const int d = orow0 - 128 + r;
                f16x4 pk = { (_Float16)acc[af][0][r], (_Float16)acc[af][1][r],
                             (_Float16)acc[af][2][r], (_Float16)acc[af][3][r] };
                *(f16x4*)(hT + ((size_t)b * CC + d) * NN + n0 + ln * 4) = pk;
            }
        }
    }
}

// ---------------------------------------------------------------------------
// Kernel 2: fp16 MFMA flash attention, Tq=64, Tm=64, 4 symmetric waves.
// Prefetches (next f-tile, this hv-tile) are issued AFTER barrier 1 so the
// compiler's vmcnt(0)-before-barrier drain lands at barrier 2 with the whole
// QK^T+softmax region (~700 cyc) as latency cover. Single-buffered regs.
// Rescale skipped (exact) when all alphas == 1 via wave-uniform ballot.
// ---------------------------------------------------------------------------
__global__ __launch_bounds__(256, 2) void attn16_kernel(
    const _Float16* __restrict__ fb, const _Float16* __restrict__ gb,
    const _Float16* __restrict__ hT, const float* __restrict__ inp,
    const float* __restrict__ gamma, float* __restrict__ out)
{
    __shared__ __align__(16) _Float16 g_s[64][72];
    __shared__ __align__(16) _Float16 f_s[64][72];
    __shared__ __align__(16) _Float16 p_s[64][72];
    __shared__ float alpha_s[64];
    __shared__ float l_s[64];

    const int b = blockIdx.x, q0 = blockIdx.y * 64, t = threadIdx.x;
    const int w = t >> 6, lane = t & 63, quad = lane >> 4, ln = lane & 15;
    const int row = t >> 2, kq = t & 3;
    const int dbase = w * 64;

    // stage g tile [64 q][64 k] once (already log2e-scaled by proj)
    {
        const _Float16* src = gb + ((size_t)b * NN + q0 + row) * KP + kq * 16;
        *(f16x8*)&g_s[row][kq * 16]     = *(const f16x8*)(src);
        *(f16x8*)&g_s[row][kq * 16 + 8] = *(const f16x8*)(src + 8);
    }
    // preload f tile 0 into registers
    f16x8 fr0, fr1;
    {
        const _Float16* src = fb + ((size_t)b * NN + row) * KP + kq * 16;
        fr0 = *(const f16x8*)(src);
        fr1 = *(const f16x8*)(src + 8);
    }
    __syncthreads();   // g_s visible

    // hoist loop-invariant A-fragments of QK^T
    f16x8 ag[2];
    ag[0] = *(const f16x8*)&g_s[w * 16 + ln][quad * 8];
    ag[1] = *(const f16x8*)&g_s[w * 16 + ln][32 + quad * 8];

    float m_run[4] = {-1e30f, -1e30f, -1e30f, -1e30f};
    float l_run[4] = {0.f, 0.f, 0.f, 0.f};
    f32x4 acc[4][4] = {};
    f16x8 hv[2][4];

    #pragma unroll 1
    for (int mt = 0; mt < NN / 64; mt++) {
        const int m0 = mt * 64;

        // current f tile regs -> LDS
        *(f16x8*)&f_s[row][kq * 16]     = fr0;
        *(f16x8*)&f_s[row][kq * 16 + 8] = fr1;
        __syncthreads();   // barrier 1: f_s ready

        // issue prefetches NOW: they drain at barrier 2, covered by QK+softmax
        {
            const int m0n = ((mt + 1) & 63) * 64;   // wrap: harmless reload
            const _Float16* srcf = fb + ((size_t)b * NN + m0n + row) * KP + kq * 16;
            fr0 = *(const f16x8*)(srcf);
            fr1 = *(const f16x8*)(srcf + 8);
            #pragma unroll
            for (int ks = 0; ks < 2; ks++)
                #pragma unroll
                for (int df = 0; df < 4; df++)
                    hv[ks][df] = *(const f16x8*)(hT +
                        ((size_t)b * CC + dbase + df * 16 + ln) * NN + m0 + ks * 32 + quad * 8);
        }

        // ---- QK^T for this wave's q-stripe ----
        f32x4 S[4] = {};
        #pragma unroll
        for (int ks = 0; ks < 2; ks++) {
            #pragma unroll
            for (int mf = 0; mf < 4; mf++) {
                f16x8 bf = *(const f16x8*)&f_s[mf * 16 + ln][ks * 32 + quad * 8];
                S[mf] = MFMA16(ag[ks], bf, S[mf]);
            }
        }

        // ---- online softmax (base-2), rows q = w*16 + quad*4 + r ----
        #pragma unroll
        for (int r = 0; r < 4; r++) {
            float mx = fmaxf(fmaxf(S[0][r], S[1][r]), fmaxf(S[2][r], S[3][r]));
            mx = max16(mx);
            float mnew = fmaxf(m_run[r], mx);
            float al   = fast_exp2(m_run[r] - mnew);
            float p0 = fast_exp2(S[0][r] - mnew);
            float p1 = fast_exp2(S[1][r] - mnew);
            float p2 = fast_exp2(S[2][r] - mnew);
            float p3 = fast_exp2(S[3][r] - mnew);
            float sum = sum16((p0 + p1) + (p2 + p3));
            l_run[r] = l_run[r] * al + sum;
            m_run[r] = mnew;
            const int qrow = w * 16 + quad * 4 + r;
            if (ln == 0) alpha_s[qrow] = al;
            f16x4 pk = { (_Float16)p0, (_Float16)p1, (_Float16)p2, (_Float16)p3 };
            *(f16x4*)&p_s[qrow][ln * 4] = pk;   // permuted col m' = ln*4 + mf
        }
        __syncthreads();   // barrier 2: p_s/alpha_s visible (+ prefetch drain)

        // ---- rescale (skip when all alphas == 1: exact) ----
        float al_[4][4];
        bool need = false;
        #pragma unroll
        for (int qf = 0; qf < 4; qf++)
            #pragma unroll
            for (int r = 0; r < 4; r++) {
                al_[qf][r] = alpha_s[qf * 16 + quad * 4 + r];
                need |= (al_[qf][r] != 1.0f);
            }
        if (__ballot(need)) {
            #pragma unroll
            for (int qf = 0; qf < 4; qf++)
                #pragma unroll
                for (int df = 0; df < 4; df++)
                    #pragma unroll
                    for (int r = 0; r < 4; r++)
                        acc[qf][df][r] *= al_[qf][r];
        }

        // ---- PV: P x h^T over this wave's 64 channels ----
        #pragma unroll
        for (int ks = 0; ks < 2; ks++) {
            #pragma unroll
            for (int qf = 0; qf < 4; qf++) {
                f16x8 ap = *(const f16x8*)&p_s[qf * 16 + ln][ks * 32 + quad * 8];
                #pragma unroll
                for (int df = 0; df < 4; df++)
                    acc[qf][df] = MFMA16(ap, hv[ks][df], acc[qf][df]);
            }
        }
    }

    // ---- exchange l across waves, fused epilogue ----
    if (ln == 0) {
        #pragma unroll
        for (int r = 0; r < 4; r++) l_s[w * 16 + quad * 4 + r] = l_run[r];
    }
    __syncthreads();

    const float gam = gamma[0];
    #pragma unroll
    for (int qf = 0; qf < 4; qf++) {
        #pragma unroll
        for (int r = 0; r < 4; r++) {
            const int q = qf * 16 + quad * 4 + r;
            const float linv = 1.0f / l_s[q];
            #pragma unroll
            for (int df = 0; df < 4; df++) {
                const int d = dbase + df * 16 + ln;
                size_t idx = ((size_t)b * NN + q0 + q) * CC + d;
                out[idx] = fmaf(gam, acc[qf][df][r] * linv, inp[idx]);
            }
        }
    }
}

// ---------------------------------------------------------------------------
extern "C" void kernel_launch(void* const* d_in, const int* in_sizes, int n_in,
                              void* d_out, int out_size, void* d_ws, size_t ws_size,
                              hipStream_t stream) {
    const float* input = (const float*)d_in[0];
    const float* nms   = (const float*)d_in[1];
    const float* WF    = (const float*)d_in[2];
    const float* WG    = (const float*)d_in[3];
    const float* WH    = (const float*)d_in[4];
    const float* gamma = (const float*)d_in[5];
    float* out = (float*)d_out;

    // workspace: W16 (192 KB) | fb16 (4 MB) | gb16 (4 MB) | hT16 (16 MB)
    char* ws = (char*)d_ws;
    _Float16* W16  = (_Float16*)ws;
    _Float16* fb16 = (_Float16*)(ws + 196608);
    _Float16* gb16 = (_Float16*)(ws + 196608 + 4194304);
    _Float16* hT16 = (_Float16*)(ws + 196608 + 2 * 4194304);

    wconv_kernel<<<96, 256, 0, stream>>>(WF, WG, WH, W16);
    proj16_kernel<<<dim3(NN / 64, BB), 256, 0, stream>>>(nms, W16, fb16, gb16, hT16);
    attn16_kernel<<<dim3(BB, NN / 64), 256, 0, stream>>>(fb16, gb16, hT16, input, gamma, out);
}